// Round 1
// baseline (433.708 us; speedup 1.0000x reference)
//
#include <hip/hip_runtime.h>

// x:   [N=256, 3, 3, num=256, F=128] fp32, C-order
// out: [N=256, 3, 3, G=128,  F=128] fp32
// For each (n, g, f): pick matrix 2g or 2g+1 with larger acos(clip((tr-1)/2,-1,1)).
// acos is strictly decreasing => pick candidate 1 iff c1 < c0 (clip kept for tie
// semantics when both traces saturate); ties -> candidate 0 (argmax first-max).

__global__ __launch_bounds__(256) void pool_space_kernel(
    const float4* __restrict__ x, float4* __restrict__ out)
{
    constexpr int FV = 32;                     // F/4
    constexpr int G  = 128;
    constexpr int IN_E_STRIDE  = 256 * FV;     // num * F/4 = 8192 float4 per (i,j)
    constexpr int IN_N_STRIDE  = 9 * IN_E_STRIDE;   // 73728
    constexpr int OUT_E_STRIDE = G * FV;       // 4096
    constexpr int OUT_N_STRIDE = 9 * OUT_E_STRIDE;  // 36864

    const int tid = blockIdx.x * blockDim.x + threadIdx.x;
    const int fv = tid & (FV - 1);
    const int g  = (tid >> 5) & (G - 1);
    const int n  = tid >> 12;

    const int inBase  = n * IN_N_STRIDE + (2 * g) * FV + fv;
    const int outBase = n * OUT_N_STRIDE + g * FV + fv;

    float4 a0[9], a1[9];
#pragma unroll
    for (int e = 0; e < 9; ++e) {
        a0[e] = x[inBase + e * IN_E_STRIDE];         // candidate 0 (num = 2g)
        a1[e] = x[inBase + e * IN_E_STRIDE + FV];    // candidate 1 (num = 2g+1)
    }

    const float* p0 = reinterpret_cast<const float*>(a0);
    const float* p1 = reinterpret_cast<const float*>(a1);
    float4 r[9];
    float* pr = reinterpret_cast<float*>(r);

#pragma unroll
    for (int k = 0; k < 4; ++k) {
        // trace = m[0][0] + m[1][1] + m[2][2]  (same add order as reference)
        const float tr0 = p0[0 * 4 + k] + p0[4 * 4 + k] + p0[8 * 4 + k];
        const float tr1 = p1[0 * 4 + k] + p1[4 * 4 + k] + p1[8 * 4 + k];
        const float c0 = fminf(fmaxf((tr0 - 1.0f) * 0.5f, -1.0f), 1.0f);
        const float c1 = fminf(fmaxf((tr1 - 1.0f) * 0.5f, -1.0f), 1.0f);
        const bool pick1 = (c1 < c0);   // acos decreasing: smaller c => larger angle
#pragma unroll
        for (int e = 0; e < 9; ++e) {
            pr[e * 4 + k] = pick1 ? p1[e * 4 + k] : p0[e * 4 + k];
        }
    }

#pragma unroll
    for (int e = 0; e < 9; ++e) {
        out[outBase + e * OUT_E_STRIDE] = r[e];
    }
}

extern "C" void kernel_launch(void* const* d_in, const int* in_sizes, int n_in,
                              void* d_out, int out_size, void* d_ws, size_t ws_size,
                              hipStream_t stream) {
    const float4* x = reinterpret_cast<const float4*>(d_in[0]);
    float4* out = reinterpret_cast<float4*>(d_out);

    // total threads = N * G * F/4 = 256 * 128 * 32 = 1,048,576
    const int threads = 256;
    const int blocks = (256 * 128 * 32) / threads;  // 4096
    pool_space_kernel<<<blocks, threads, 0, stream>>>(x, out);
}

// Round 3
// 415.431 us; speedup vs baseline: 1.0440x; 1.0440x over previous
//
#include <hip/hip_runtime.h>

// x:   [N=256, 3, 3, num=256, F=128] fp32, C-order
// out: [N=256, 3, 3, G=128,  F=128] fp32
// Per (n,g,f): keep matrix 2g or 2g+1 with larger acos(clip((tr-1)/2,-1,1)).
// acos strictly decreasing => pick candidate 1 iff clip(c1) < clip(c0);
// ties -> candidate 0 (argmax first-max semantics). Round-1 version verified
// absmax == 0 with identical selection math.

typedef float vf4 __attribute__((ext_vector_type(4)));  // native clang vector:
// required because __builtin_nontemporal_load/store rejects HIP_vector_type.

__global__ __launch_bounds__(256) void pool_space_kernel(
    const vf4* __restrict__ x, vf4* __restrict__ out)
{
    constexpr int FV    = 32;              // F/4
    constexpr int G     = 128;
    constexpr int IN_E  = 256 * FV;        // 8192 vf4 per (i,j) plane
    constexpr int IN_N  = 9 * IN_E;
    constexpr int OUT_E = G * FV;          // 4096
    constexpr int OUT_N = 9 * OUT_E;

    const int tid = blockIdx.x * blockDim.x + threadIdx.x;
    const int fv  = tid & (FV - 1);
    const int g   = (tid >> 5) & (G - 1);
    const int n   = tid >> 12;

    const int inBase  = n * IN_N + (2 * g) * FV + fv;
    const int outBase = n * OUT_N + g * FV + fv;

    // Issue all 18 loads up front (max MLP). Diagonals first (they gate the pick).
    vf4 d0a = __builtin_nontemporal_load(&x[inBase + 0 * IN_E]);
    vf4 d0b = __builtin_nontemporal_load(&x[inBase + 0 * IN_E + FV]);
    vf4 d4a = __builtin_nontemporal_load(&x[inBase + 4 * IN_E]);
    vf4 d4b = __builtin_nontemporal_load(&x[inBase + 4 * IN_E + FV]);
    vf4 d8a = __builtin_nontemporal_load(&x[inBase + 8 * IN_E]);
    vf4 d8b = __builtin_nontemporal_load(&x[inBase + 8 * IN_E + FV]);

    vf4 oa[6], ob[6];
    constexpr int OD[6] = {1, 2, 3, 5, 6, 7};
#pragma unroll
    for (int i = 0; i < 6; ++i) {
        oa[i] = __builtin_nontemporal_load(&x[inBase + OD[i] * IN_E]);
        ob[i] = __builtin_nontemporal_load(&x[inBase + OD[i] * IN_E + FV]);
    }

    // Per-component pick: pk[k] true -> take candidate 1.
    bool pk[4];
#pragma unroll
    for (int k = 0; k < 4; ++k) {
        const float tr0 = d0a[k] + d4a[k] + d8a[k];
        const float tr1 = d0b[k] + d4b[k] + d8b[k];
        const float c0 = fminf(fmaxf((tr0 - 1.0f) * 0.5f, -1.0f), 1.0f);
        const float c1 = fminf(fmaxf((tr1 - 1.0f) * 0.5f, -1.0f), 1.0f);
        pk[k] = (c1 < c0);
    }

    auto sel = [&](vf4 a, vf4 b) {
        vf4 r;
        r[0] = pk[0] ? b[0] : a[0];
        r[1] = pk[1] ? b[1] : a[1];
        r[2] = pk[2] ? b[2] : a[2];
        r[3] = pk[3] ? b[3] : a[3];
        return r;
    };

    // Diagonal outputs reuse the already-loaded registers (no reload).
    __builtin_nontemporal_store(sel(d0a, d0b), &out[outBase + 0 * OUT_E]);
    __builtin_nontemporal_store(sel(d4a, d4b), &out[outBase + 4 * OUT_E]);
    __builtin_nontemporal_store(sel(d8a, d8b), &out[outBase + 8 * OUT_E]);
#pragma unroll
    for (int i = 0; i < 6; ++i) {
        __builtin_nontemporal_store(sel(oa[i], ob[i]), &out[outBase + OD[i] * OUT_E]);
    }
}

extern "C" void kernel_launch(void* const* d_in, const int* in_sizes, int n_in,
                              void* d_out, int out_size, void* d_ws, size_t ws_size,
                              hipStream_t stream) {
    const vf4* x = reinterpret_cast<const vf4*>(d_in[0]);
    vf4* out = reinterpret_cast<vf4*>(d_out);

    // total threads = N * G * F/4 = 256 * 128 * 32 = 1,048,576
    const int threads = 256;
    const int blocks = (256 * 128 * 32) / threads;  // 4096
    pool_space_kernel<<<blocks, threads, 0, stream>>>(x, out);
}